// Round 6
// baseline (992.166 us; speedup 1.0000x reference)
//
#include <hip/hip_runtime.h>
#include <cstddef>

// DifferentiableRollout: x_{t+1} = x + DT * ( tanh([x,u]@W1 + b1) @ W2 + b2 )
// B=1024, T=200, SD=64, CD=32, H=512.  fp32 only (bf16 amplifies past the
// 1.245 absmax threshold; fp32 reorder noise alone is 0.25).
//
// History:
//  R5-R7: 80 weight floats/thread demanded in regs -> allocator never grants
//    >64 VGPR at 1024 thr; weights remat-streamed from L2 (790 us, VALU 77%).
//  R8/R9: pinning / straight-line 48-load stream -> pressure > 64-reg grant
//    -> in-loop scratch spill of the weights: 28 GB HBM, ~8.5 ms.
//  R10: unroll-1 8-load chunks: spill GONE (VGPR 52, HBM back to 65 MB) but
//    1045 us, VALU 54%: each chunk issues-then-waits, exposing ~250 cyc L2
//    latency x 6 chunks; 4 waves/SIMD (~100 cyc FMA/chunk) can't cover it.
//
// R11 (this round): software-pipeline INSIDE the spill-safe loop.
//  - Two 8-float buffers wA/wB; phase p consumes chunk p while issuing
//    loads for chunk (p+2) mod 6.  Phases 4/5 therefore prefetch NEXT
//    step's chunks 0/1 -- W1 is time-invariant so cross-step, cross-barrier
//    register prefetch is valid.  The W1 L2 stream (196 KB/CU/step) now
//    overlaps the tanh/GEMM2/reduce tail, where the L2 pipe is idle
//    (W2 is LDS-resident).
//  - Inner loop does 2 phases/iteration with #pragma unroll 1 (the fence
//    R10 proved keeps pressure bounded); in-flight = 16 weight regs,
//    total demand ~58 < 64.
//  - Everything else identical to R10: W2 (128 KB) LDS-resident loaded
//    once; balanced tanh; pbuf aliasing; ctrl prefetch; 4 barriers.
//  Verify: dur 520-700 us, VALU 62-75%, FETCH ~14 MB / WRITE ~51 MB
//  (spill detector), absmax 0.25.

constexpr int B_  = 1024;
constexpr int T_  = 200;
constexpr int SD_ = 64;
constexpr int CD_ = 32;
constexpr int H_  = 512;
constexpr int KD_ = SD_ + CD_;   // 96
constexpr float DT_ = 0.1f;
constexpr int ROWS_ = 4;
constexpr int THREADS_ = 1024;
constexpr int KHALF_ = 48;       // K split per g
constexpr int WCHUNK_ = 8;       // W1 loads per phase
constexpr int NCHUNK_ = KHALF_ / WCHUNK_;   // 6 phases
constexpr int CHUNK_ = 32;       // W2 rows per wave (H / 16 waves)

__global__ __launch_bounds__(THREADS_)
void rollout_r11_kernel(
    const float* __restrict__ x0,     // [B, SD]
    const float* __restrict__ ctrl,   // [B, T, CD]
    const float* __restrict__ W1,     // [KD, H]
    const float* __restrict__ b1,     // [H]
    const float* __restrict__ W2,     // [H, SD]
    const float* __restrict__ b2,     // [SD]
    float* __restrict__ out)          // [B, T+1, SD]
{
    __shared__ float w2s[H_][SD_];           // 128 KB: W2, loaded once
    __shared__ float xcT[KD_][ROWS_];        // state+control, transposed
    __shared__ float pbuf[ROWS_][H_];        // GEMM1 partials, then tanh acts
    __shared__ float part2[ROWS_][16][SD_];  // GEMM2 partials [r][wv][s]

    const int tid = threadIdx.x;
    const int r0  = blockIdx.x * ROWS_;

    // ---- GEMM1 mapping: thread (g, j) streams W1[kbase..kbase+48)[j] ----
    const int j     = tid & (H_ - 1);   // 0..511
    const int g     = tid >> 9;         // 0 or 1 (wave-uniform)
    const int kbase = g * KHALF_;
    const float* __restrict__ wcol = W1 + (size_t)kbase * H_ + j;

    // ---- W2 -> LDS (flat coalesced copy, 8 float4 per thread) ----
    {
        const float4* __restrict__ src = (const float4*)W2;
        float4* dst = (float4*)&w2s[0][0];
        #pragma unroll
        for (int i = 0; i < 8; ++i)
            dst[i * THREADS_ + tid] = src[i * THREADS_ + tid];
    }

    // ---- GEMM2 mapping: wave wv covers H-slice [32wv, 32wv+32) ----
    const int wv = tid >> 6;            // 0..15 (wave id)
    const int sl = tid & 63;
    const int jb = wv * CHUNK_;

    const float bj = b1[j];

    // reduce/update mapping (tid < 256)
    const int rf = (tid >> 6) & 3;
    const int sf = tid & 63;
    const float bs = b2[sf];

    // ctrl loader: tids [512, 640) -- g==1 threads
    const int  lt = tid - 512;
    const bool loader = (lt >= 0) && (lt < ROWS_ * CD_);
    const int  lr = (lt >> 5) & 3;
    const int  lc = lt & 31;
    const size_t ctrl_base = (size_t)(r0 + lr) * T_ * CD_ + lc;

    // ---- init: x0 into xcT + states[:,0,:], ctrl[0] into xcT ----
    if (tid < ROWS_ * SD_) {
        const float v = x0[(size_t)(r0 + rf) * SD_ + sf];
        xcT[sf][rf] = v;
        out[(size_t)(r0 + rf) * (T_ + 1) * SD_ + sf] = v;
    }
    if (loader) xcT[SD_ + lc][lr] = ctrl[ctrl_base];

    // ---- prologue: prefetch chunks 0 and 1 into the two buffers ----
    float wA[WCHUNK_], wB[WCHUNK_];
    #pragma unroll
    for (int u = 0; u < WCHUNK_; ++u)
        wA[u] = wcol[(size_t)u * H_];
    #pragma unroll
    for (int u = 0; u < WCHUNK_; ++u)
        wB[u] = wcol[(size_t)(WCHUNK_ + u) * H_];

    __syncthreads();   // covers xcT init AND w2s copy

    for (int t = 0; t < T_; ++t) {
        // ---- prefetch next step's controls into a register ----
        float cpre = 0.f;
        if (loader && (t + 1 < T_))
            cpre = ctrl[ctrl_base + (size_t)(t + 1) * CD_];

        // ---- GEMM1: consume chunk p, prefetch chunk (p+2) mod 6 ----
        // Phases 4/5 prefetch NEXT step's chunks 0/1 (W1 is invariant).
        float a0 = 0.f, a1 = 0.f, a2 = 0.f, a3 = 0.f;
        #pragma unroll 1           // spill fence: 2 phases live at a time
        for (int pp = 0; pp < NCHUNK_; pp += 2) {
            // phase pp: consume wA, refill wA with chunk pp+2 (wrapped)
            #pragma unroll
            for (int u = 0; u < WCHUNK_; ++u) {
                const float4 xv = *(const float4*)&xcT[kbase + pp * WCHUNK_ + u][0];
                a0 += xv.x * wA[u];
                a1 += xv.y * wA[u];
                a2 += xv.z * wA[u];
                a3 += xv.w * wA[u];
            }
            {
                int c = pp + 2; if (c >= NCHUNK_) c -= NCHUNK_;
                const float* __restrict__ p = wcol + (size_t)c * WCHUNK_ * H_;
                #pragma unroll
                for (int u = 0; u < WCHUNK_; ++u) wA[u] = p[(size_t)u * H_];
            }
            // phase pp+1: consume wB, refill wB with chunk pp+3 (wrapped)
            #pragma unroll
            for (int u = 0; u < WCHUNK_; ++u) {
                const float4 xv = *(const float4*)&xcT[kbase + (pp + 1) * WCHUNK_ + u][0];
                a0 += xv.x * wB[u];
                a1 += xv.y * wB[u];
                a2 += xv.z * wB[u];
                a3 += xv.w * wB[u];
            }
            {
                int c = pp + 3; if (c >= NCHUNK_) c -= NCHUNK_;
                const float* __restrict__ p = wcol + (size_t)c * WCHUNK_ * H_;
                #pragma unroll
                for (int u = 0; u < WCHUNK_; ++u) wB[u] = p[(size_t)u * H_];
            }
        }
        // each half writes the partials the OTHER half will finish
        if (g == 0) { pbuf[2][j] = a2;  pbuf[3][j] = a3; }
        else        { pbuf[0][j] = a0;  pbuf[1][j] = a1; }
        __syncthreads();   // A: partials visible; step-t xcT reads done

        // ---- balanced tanh: g=0 rows 0-1, g=1 rows 2-3 ----
        if (g == 0) {
            pbuf[0][j] = tanhf(bj + a0 + pbuf[0][j]);
            pbuf[1][j] = tanhf(bj + a1 + pbuf[1][j]);
        } else {
            pbuf[2][j] = tanhf(bj + a2 + pbuf[2][j]);
            pbuf[3][j] = tanhf(bj + a3 + pbuf[3][j]);
            if (loader && (t + 1 < T_))
                xcT[SD_ + lc][lr] = cpre;   // step-t xcT reads done at A
        }
        __syncthreads();   // B: activations visible

        // ---- GEMM2: wave wv, j in [jb, jb+32), W2 from LDS ----
        {
            float p0 = 0.f, p1 = 0.f, p2 = 0.f, p3 = 0.f;
            #pragma unroll
            for (int i4 = 0; i4 < CHUNK_; i4 += 4) {
                // 4 W2 rows, lane-consecutive (conflict-free), reused x4 rows
                const float wa = w2s[jb + i4 + 0][sl];
                const float wb = w2s[jb + i4 + 1][sl];
                const float wc = w2s[jb + i4 + 2][sl];
                const float wd = w2s[jb + i4 + 3][sl];
                const float4 h0 = *(const float4*)&pbuf[0][jb + i4];
                const float4 h1 = *(const float4*)&pbuf[1][jb + i4];
                const float4 h2 = *(const float4*)&pbuf[2][jb + i4];
                const float4 h3 = *(const float4*)&pbuf[3][jb + i4];
                p0 += h0.x * wa + h0.y * wb + h0.z * wc + h0.w * wd;
                p1 += h1.x * wa + h1.y * wb + h1.z * wc + h1.w * wd;
                p2 += h2.x * wa + h2.y * wb + h2.z * wc + h2.w * wd;
                p3 += h3.x * wa + h3.y * wb + h3.z * wc + h3.w * wd;
            }
            part2[0][wv][sl] = p0;      // lane-consecutive: conflict-free
            part2[1][wv][sl] = p1;
            part2[2][wv][sl] = p2;
            part2[3][wv][sl] = p3;
        }
        __syncthreads();   // C: part2 visible

        // ---- 16-chunk reduce + state update: tid < 256 ----
        if (tid < ROWS_ * SD_) {
            float acc = part2[rf][0][sf];
            #pragma unroll
            for (int c = 1; c < 16; ++c) acc += part2[rf][c][sf];
            const float xnew = xcT[sf][rf] + DT_ * (acc + bs);
            xcT[sf][rf] = xnew;
            out[(size_t)(r0 + rf) * (T_ + 1) * SD_ + (size_t)(t + 1) * SD_ + sf] = xnew;
        }
        __syncthreads();   // D: new state visible; part2 reads done
    }
}

extern "C" void kernel_launch(void* const* d_in, const int* in_sizes, int n_in,
                              void* d_out, int out_size, void* d_ws, size_t ws_size,
                              hipStream_t stream) {
    const float* x0   = (const float*)d_in[0];
    const float* ctrl = (const float*)d_in[1];
    const float* W1   = (const float*)d_in[2];
    const float* b1   = (const float*)d_in[3];
    const float* W2   = (const float*)d_in[4];
    const float* b2   = (const float*)d_in[5];
    float* out = (float*)d_out;

    dim3 grid(B_ / ROWS_);      // 256 blocks -> 1 per CU (persistent)
    dim3 block(THREADS_);
    rollout_r11_kernel<<<grid, block, 0, stream>>>(x0, ctrl, W1, b1, W2, b2, out);
}

// Round 7
// 706.975 us; speedup vs baseline: 1.4034x; 1.4034x over previous
//
#include <hip/hip_runtime.h>
#include <cstddef>

// DifferentiableRollout: x_{t+1} = x + DT * ( tanh([x,u]@W1 + b1) @ W2 + b2 )
// B=1024, T=200, SD=64, CD=32, H=512.  fp32 only (bf16 amplifies past the
// 1.245 absmax threshold; fp32 reorder noise alone is 0.25).
//
// History:
//  R5 (best, 788 us): weights preloaded into arrays OUTSIDE the t-loop;
//    compiler remats them as just-in-time L2 loads inside the loop.  The
//    ONLY schedule seen that neither spills nor stalls.  VALU 77%, but
//    ~912 issue-inst/thread/step vs a 320-FMA floor.
//  R8/R9: explicit residency (pins / inline loads) -> in-loop scratch
//    spill, 28 GB HBM, ~8.5 ms.  R10/R11: manual chunking / double-buffer
//    prefetch -> latency exposure or index overhead, 962-1045 us.
//  => Keep R5's source shape for all weight access.  Attack issue COUNT.
//
// R12 (this round): packed fp32 (v_pk_fma_f32, VOP3P) -- 2 MACs/issue.
//  - GEMM1 packs along J: thread = (ks = tid>>8 in [0,4), jp = tid&255);
//    owns j-pair {2jp, 2jp+1}, K-slice [24ks, 24ks+24).  W1 preload is
//    float2 (remat -> dwordx2: 24 loads vs 48, addr halved).  Inner:
//    24 x (1 broadcast ds_read_b128 of xcT + 4 pk_fma).  Partials to
//    part1[4][4][512] (32 KB); finish = all 1024 threads: sum 4 slices
//    (f2), +bias, 2 tanh, write pbuf[4][512] (R5 layout).
//  - GEMM2 packs along H (the accumulation dim): pairs (h,h+1) are
//    contiguous in pbuf[r][.], so the float4 read feeds 2 pk_fma.
//    W2 preload/remat + (wv,sl) mapping + part2 + reduce = R5-identical.
//  - w2s-in-LDS dropped (R5 proved remat GEMM2 fine).  LDS ~57.5 KB.
//  Verify: dur 450-580, VALU 65-80%, FETCH ~14 MB / WRITE ~51 MB
//  (spill tripwire), VGPR 52-64, absmax ~0.25.

constexpr int B_  = 1024;
constexpr int T_  = 200;
constexpr int SD_ = 64;
constexpr int CD_ = 32;
constexpr int H_  = 512;
constexpr int KD_ = SD_ + CD_;   // 96
constexpr float DT_ = 0.1f;
constexpr int ROWS_ = 4;
constexpr int THREADS_ = 1024;
constexpr int KSLICES_ = 4;      // GEMM1 K split
constexpr int KLEN_ = KD_ / KSLICES_;   // 24
constexpr int CHUNK_ = 32;       // W2 rows per wave (H / 16 waves)

typedef float f2 __attribute__((ext_vector_type(2)));

__global__ __launch_bounds__(THREADS_)
void rollout_r12_kernel(
    const float* __restrict__ x0,     // [B, SD]
    const float* __restrict__ ctrl,   // [B, T, CD]
    const float* __restrict__ W1,     // [KD, H]
    const float* __restrict__ b1,     // [H]
    const float* __restrict__ W2,     // [H, SD]
    const float* __restrict__ b2,     // [SD]
    float* __restrict__ out)          // [B, T+1, SD]
{
    __shared__ float xcT[KD_][ROWS_];           // state+control, transposed
    __shared__ float part1[KSLICES_][ROWS_][H_]; // GEMM1 rank-24 partials, 32 KB
    __shared__ float pbuf[ROWS_][H_];           // tanh activations
    __shared__ float part2[ROWS_][16][SD_];     // GEMM2 partials [r][wv][s]

    const int tid = threadIdx.x;
    const int r0  = blockIdx.x * ROWS_;

    // ---- GEMM1 mapping: (ks, jp) -> j-pair column of one K-slice ----
    const int jp    = tid & 255;        // j-pair index, j0 = 2*jp
    const int ks    = tid >> 8;         // 0..3 (wave-uniform)
    const int j0    = jp * 2;
    const int kbase = ks * KLEN_;
    f2 w1p[KLEN_];
    #pragma unroll
    for (int i = 0; i < KLEN_; ++i)
        w1p[i] = *(const f2*)&W1[(size_t)(kbase + i) * H_ + j0];  // coalesced x2

    // ---- GEMM2 mapping: wave wv owns W2 rows [32wv,32wv+32), lane sl ----
    const int wv = tid >> 6;            // 0..15 (wave id)
    const int sl = tid & 63;
    const int jb = wv * CHUNK_;
    float w2p[CHUNK_];
    #pragma unroll
    for (int i = 0; i < CHUNK_; ++i)
        w2p[i] = W2[(size_t)(jb + i) * SD_ + sl];        // coalesced

    // ---- finish mapping: (rF, jjF pair) ----
    const int rF  = tid >> 8;           // 0..3
    const int jjF = (tid & 255) * 2;
    const f2 bj2 = {b1[jjF], b1[jjF + 1]};

    // reduce/update mapping (tid < 256)
    const int rf = (tid >> 6) & 3;
    const int sf = tid & 63;
    const float bs = b2[sf];

    // ctrl loader: tids [512, 640)
    const int  lt = tid - 512;
    const bool loader = (lt >= 0) && (lt < ROWS_ * CD_);
    const int  lr = (lt >> 5) & 3;
    const int  lc = lt & 31;
    const size_t ctrl_base = (size_t)(r0 + lr) * T_ * CD_ + lc;

    // ---- init: x0 into xcT + states[:,0,:], ctrl[0] into xcT ----
    if (tid < ROWS_ * SD_) {
        const float v = x0[(size_t)(r0 + rf) * SD_ + sf];
        xcT[sf][rf] = v;
        out[(size_t)(r0 + rf) * (T_ + 1) * SD_ + sf] = v;
    }
    if (loader) xcT[SD_ + lc][lr] = ctrl[ctrl_base];
    __syncthreads();

    for (int t = 0; t < T_; ++t) {
        // ---- prefetch next step's controls into a register ----
        float cpre = 0.f;
        if (loader && (t + 1 < T_))
            cpre = ctrl[ctrl_base + (size_t)(t + 1) * CD_];

        // ---- GEMM1 rank-24 partials: 4 rows x j-pair, packed fp32 ----
        f2 a0 = {0.f, 0.f}, a1 = {0.f, 0.f}, a2 = {0.f, 0.f}, a3 = {0.f, 0.f};
        #pragma unroll
        for (int i = 0; i < KLEN_; ++i) {
            const float4 xv = *(const float4*)&xcT[kbase + i][0];  // broadcast
            const f2 w = w1p[i];
            a0 = __builtin_elementwise_fma(w, (f2){xv.x, xv.x}, a0);
            a1 = __builtin_elementwise_fma(w, (f2){xv.y, xv.y}, a1);
            a2 = __builtin_elementwise_fma(w, (f2){xv.z, xv.z}, a2);
            a3 = __builtin_elementwise_fma(w, (f2){xv.w, xv.w}, a3);
        }
        *(f2*)&part1[ks][0][j0] = a0;
        *(f2*)&part1[ks][1][j0] = a1;
        *(f2*)&part1[ks][2][j0] = a2;
        *(f2*)&part1[ks][3][j0] = a3;
        __syncthreads();   // A: part1 visible; all step-t xcT reads done

        // ---- finish: sum 4 slices + bias, tanh x2, all threads ----
        {
            f2 s = *(const f2*)&part1[0][rF][jjF];
            s += *(const f2*)&part1[1][rF][jjF];
            s += *(const f2*)&part1[2][rF][jjF];
            s += *(const f2*)&part1[3][rF][jjF];
            s += bj2;
            f2 hv;
            hv.x = tanhf(s.x);
            hv.y = tanhf(s.y);
            *(f2*)&pbuf[rF][jjF] = hv;
            if (loader && (t + 1 < T_))
                xcT[SD_ + lc][lr] = cpre;   // step-t xcT reads done at A
        }
        __syncthreads();   // B: activations visible

        // ---- GEMM2: wave wv, h in [jb, jb+32), packed along H ----
        {
            f2 q0 = {0.f, 0.f}, q1 = {0.f, 0.f}, q2 = {0.f, 0.f}, q3 = {0.f, 0.f};
            #pragma unroll
            for (int i4 = 0; i4 < CHUNK_; i4 += 4) {
                const f2 wab = {w2p[i4 + 0], w2p[i4 + 1]};
                const f2 wcd = {w2p[i4 + 2], w2p[i4 + 3]};
                const float4 h0 = *(const float4*)&pbuf[0][jb + i4];  // broadcast
                const float4 h1 = *(const float4*)&pbuf[1][jb + i4];
                const float4 h2 = *(const float4*)&pbuf[2][jb + i4];
                const float4 h3 = *(const float4*)&pbuf[3][jb + i4];
                q0 = __builtin_elementwise_fma((f2){h0.x, h0.y}, wab, q0);
                q0 = __builtin_elementwise_fma((f2){h0.z, h0.w}, wcd, q0);
                q1 = __builtin_elementwise_fma((f2){h1.x, h1.y}, wab, q1);
                q1 = __builtin_elementwise_fma((f2){h1.z, h1.w}, wcd, q1);
                q2 = __builtin_elementwise_fma((f2){h2.x, h2.y}, wab, q2);
                q2 = __builtin_elementwise_fma((f2){h2.z, h2.w}, wcd, q2);
                q3 = __builtin_elementwise_fma((f2){h3.x, h3.y}, wab, q3);
                q3 = __builtin_elementwise_fma((f2){h3.z, h3.w}, wcd, q3);
            }
            part2[0][wv][sl] = q0.x + q0.y;   // lane-consecutive: conflict-free
            part2[1][wv][sl] = q1.x + q1.y;
            part2[2][wv][sl] = q2.x + q2.y;
            part2[3][wv][sl] = q3.x + q3.y;
        }
        __syncthreads();   // C: part2 visible

        // ---- 16-chunk reduce + state update: tid < 256 ----
        if (tid < ROWS_ * SD_) {
            float acc = part2[rf][0][sf];
            #pragma unroll
            for (int c = 1; c < 16; ++c) acc += part2[rf][c][sf];
            const float xnew = xcT[sf][rf] + DT_ * (acc + bs);
            xcT[sf][rf] = xnew;
            out[(size_t)(r0 + rf) * (T_ + 1) * SD_ + (size_t)(t + 1) * SD_ + sf] = xnew;
        }
        __syncthreads();   // D: new state visible; part2 reads done
    }
}

extern "C" void kernel_launch(void* const* d_in, const int* in_sizes, int n_in,
                              void* d_out, int out_size, void* d_ws, size_t ws_size,
                              hipStream_t stream) {
    const float* x0   = (const float*)d_in[0];
    const float* ctrl = (const float*)d_in[1];
    const float* W1   = (const float*)d_in[2];
    const float* b1   = (const float*)d_in[3];
    const float* W2   = (const float*)d_in[4];
    const float* b2   = (const float*)d_in[5];
    float* out = (float*)d_out;

    dim3 grid(B_ / ROWS_);      // 256 blocks -> 1 per CU (persistent)
    dim3 block(THREADS_);
    rollout_r12_kernel<<<grid, block, 0, stream>>>(x0, ctrl, W1, b1, W2, b2, out);
}